// Round 7
// baseline (121.882 us; speedup 1.0000x reference)
//
#include <hip/hip_runtime.h>
#include <hip/hip_bf16.h>
#include <math.h>

#define S_ 64
#define B_ 128
#define H_ 768
#define A_ 768
#define BK 32
#define NT2 24           // K-steps: 768/32

typedef __bf16 bf16_t;
typedef __attribute__((ext_vector_type(8))) __bf16 bf16x8;
typedef __attribute__((ext_vector_type(4))) __bf16 bf16x4;
typedef __attribute__((ext_vector_type(4))) float f32x4;

#define TOPIC_N   98304      // 128*768
#define IMG_N   6291456      // 64*128*768

__device__ __forceinline__ bf16x8 pack8(float4 a, float4 b) {
    bf16x8 o;
    o[0]=(bf16_t)a.x; o[1]=(bf16_t)a.y; o[2]=(bf16_t)a.z; o[3]=(bf16_t)a.w;
    o[4]=(bf16_t)b.x; o[5]=(bf16_t)b.y; o[6]=(bf16_t)b.z; o[7]=(bf16_t)b.w;
    return o;
}

__device__ __forceinline__ void glds16f(const float* g, float* l) {
    __builtin_amdgcn_global_load_lds(
        (const __attribute__((address_space(1))) uint32_t*)g,
        (__attribute__((address_space(3))) uint32_t*)l, 16, 0, 0);
}
__device__ __forceinline__ void glds16b(const bf16_t* g, bf16_t* l) {
    __builtin_amdgcn_global_load_lds(
        (const __attribute__((address_space(1))) uint32_t*)g,
        (__attribute__((address_space(3))) uint32_t*)l, 16, 0, 0);
}

// ============================================================================
// FAST PATH
// ============================================================================

// ---- prep: [topic; image; text] f32 -> bf16, one linear pass ----
__global__ __launch_bounds__(256)
void convert_kernel(const float* __restrict__ topic, const float* __restrict__ image,
                    const float* __restrict__ text, bf16_t* __restrict__ out) {
    const int i = blockIdx.x * 256 + threadIdx.x;      // 8 elems each
    const int T8 = TOPIC_N / 8, I8 = IMG_N / 8;
    const size_t e = (size_t)i * 8;
    const float* src; size_t off;
    if (i < T8)           { src = topic; off = e; }
    else if (i < T8 + I8) { src = image; off = e - TOPIC_N; }
    else                  { src = text;  off = e - TOPIC_N - IMG_N; }
    const float4* p = reinterpret_cast<const float4*>(src + off);
    float4 a = p[0], b = p[1];
    *reinterpret_cast<bf16x8*>(out + e) = pack8(a, b);
}

// ---- main GEMM: 128(M)x64(N) tile, BK=32, 4 waves (2Mx2N).
//      Triple-buffered LDS (48 KB -> 3 blocks/CU), 2-deep glds prefetch,
//      counted s_waitcnt vmcnt(4) at loop top (T4): stage(t+1) stays in
//      flight across the barrier while tile t computes. W f32 staged [k][n]
//      rotate-swizzled (column reads 2-way free); A bf16 staged with
//      chunk-swizzle (frag b128 reads 2-way free). ----
__global__ __launch_bounds__(256, 3)
void gemm_direct(const float* __restrict__ Wv, const float* __restrict__ Wq,
                 const bf16_t* __restrict__ actB,
                 const float* __restrict__ bq, const float* __restrict__ bv,
                 bf16_t* __restrict__ Vws, float* __restrict__ Qws)
{
    __shared__ float  W1[3][BK * 64];     // [k][n-chunk swizzled] f32, 8 KB each
    __shared__ bf16_t Al[3][128 * BK];    // [m][k-chunk swizzled] bf16, 8 KB each

    // XCD-chunked bijective remap, nwg = 2316 (q=289, r=4) [T1/m204]
    const int b0 = blockIdx.x;
    const int xcd = b0 & 7, ii = b0 >> 3;
    const int bid = (xcd < 4) ? (xcd * 290 + ii) : (1160 + (xcd - 4) * 289 + ii);

    const int tid = threadIdx.x;
    const bool isQ = (bid >= 2304);
    int s, tm, tn;
    if (isQ) { s = S_; tm = 0; tn = bid - 2304; }
    else     { s = bid / 36; const int t = bid % 36; tm = t / 12; tn = t % 12; }

    const float* Wsl = isQ ? Wq : (Wv + (size_t)s * H_ * A_);
    const bf16_t* Apanel;
    if (isQ || tm == 0) Apanel = actB;
    else if (tm == 1)   Apanel = actB + TOPIC_N + (size_t)s * B_ * H_;
    else                Apanel = actB + TOPIC_N + IMG_N + (size_t)s * B_ * H_;

    const int wv = tid >> 6, lane = tid & 63;
    const int wr = wv >> 1, wc = wv & 1;          // wave tile 64M x 32N
    const int fr = lane & 15, fg = lane >> 4;

    f32x4 acc[4][2];
    #pragma unroll
    for (int i = 0; i < 4; ++i)
        #pragma unroll
        for (int j = 0; j < 2; ++j)
            acc[i][j] = (f32x4){0.f, 0.f, 0.f, 0.f};

    // stage tile t1 into buffer buf: exactly 4 glds per thread
    auto stage = [&](int t1, int buf) {
        const int k0 = t1 * BK;
        #pragma unroll
        for (int q = 0; q < 2; ++q) {              // W: 8 KB, 8 instrs (2/wave)
            const int cl = (q * 4 + wv) * 64 + lane;   // 16B chunk 0..511
            const int k = cl >> 4, cc = cl & 15;
            const int cs = (cc - 2 * ((k >> 3) & 3)) & 15;   // inverse rotate
            glds16f(Wsl + (size_t)(k0 + k) * A_ + tn * 64 + cs * 4,
                    &W1[buf][(q * 4 + wv) * 256]);
        }
        #pragma unroll
        for (int q = 0; q < 2; ++q) {              // A: 8 KB, 8 instrs (2/wave)
            const int cl = (q * 4 + wv) * 64 + lane;
            const int row = cl >> 2, c = cl & 3;
            const int kc = (c - (row >> 1)) & 3;             // inverse swizzle
            glds16b(Apanel + (size_t)row * H_ + k0 + kc * 8,
                    &Al[buf][(q * 4 + wv) * 512]);
        }
    };

    // one K-step; buf = t%3 (static), buf2 = (t+2)%3 (static)
    auto kstep = [&](int t, int buf, int buf2) {
        // counted wait: stage(t) landed, stage(t+1)'s 4 glds may stay in flight
        if (t == NT2 - 1) asm volatile("s_waitcnt vmcnt(0) lgkmcnt(0)" ::: "memory");
        else              asm volatile("s_waitcnt vmcnt(4) lgkmcnt(0)" ::: "memory");
        __builtin_amdgcn_sched_barrier(0);
        __builtin_amdgcn_s_barrier();
        __builtin_amdgcn_sched_barrier(0);

        // B-frags: W1[buf] column reads (rotate-swizzled: 2-way, free) + cvt
        bf16x8 bfv[2];
        #pragma unroll
        for (int ni = 0; ni < 2; ++ni) {
            const int n = wc * 32 + ni * 16 + fr;
            const int cswz = (((n >> 2) + 2 * fg) & 15) * 4 + (n & 3);
            float bw[8];
            #pragma unroll
            for (int j = 0; j < 8; ++j)
                bw[j] = W1[buf][(fg * 8 + j) * 64 + cswz];
            bf16x8 o;
            #pragma unroll
            for (int j = 0; j < 8; ++j) o[j] = (bf16_t)bw[j];
            bfv[ni] = o;
        }
        // A-frags: chunk-swizzled b128 reads (2 lanes/bank-group, free)
        bf16x8 af[4];
        #pragma unroll
        for (int mi = 0; mi < 4; ++mi) {
            const int m = wr * 64 + mi * 16 + fr;
            const int c = (fg + (m >> 1)) & 3;
            af[mi] = *reinterpret_cast<const bf16x8*>(&Al[buf][m * BK + c * 8]);
        }

        // prefetch t+2 (lands under the next ~2 compute phases + TLP)
        if (t + 2 < NT2) stage(t + 2, buf2);

        #pragma unroll
        for (int mi = 0; mi < 4; ++mi)
            #pragma unroll
            for (int ni = 0; ni < 2; ++ni)
                acc[mi][ni] = __builtin_amdgcn_mfma_f32_16x16x32_bf16(
                    af[mi], bfv[ni], acc[mi][ni], 0, 0, 0);
    };

    stage(0, 0);
    stage(1, 1);
    #pragma unroll 1
    for (int tb = 0; tb < NT2; tb += 3) {
        kstep(tb + 0, 0, 2);
        kstep(tb + 1, 1, 0);
        kstep(tb + 2, 2, 1);
    }

    // ---- epilogue: C/D map col = lane&15, row = (lane>>4)*4 + j ----
    if (isQ) {
        #pragma unroll
        for (int ni = 0; ni < 2; ++ni) {
            const int n = tn * 64 + wc * 32 + ni * 16 + fr;
            const float bias = bq[n];
            #pragma unroll
            for (int mi = 0; mi < 4; ++mi)
                #pragma unroll
                for (int j = 0; j < 4; ++j) {
                    const int m = wr * 64 + mi * 16 + fg * 4 + j;
                    Qws[(size_t)m * A_ + n] = acc[mi][ni][j] + bias;
                }
        }
    } else {
        const float* bvrow = bv + (size_t)s * A_;
        #pragma unroll
        for (int ni = 0; ni < 2; ++ni) {
            const int n = tn * 64 + wc * 32 + ni * 16 + fr;
            const float bias = bvrow[n];
            #pragma unroll
            for (int mi = 0; mi < 4; ++mi)
                #pragma unroll
                for (int j = 0; j < 4; ++j) {
                    const int b = wr * 64 + mi * 16 + fg * 4 + j;
                    Vws[(((size_t)s * B_ + b) * 3 + tm) * A_ + n] = (bf16_t)(acc[mi][ni][j] + bias);
                }
        }
    }
}

// ---- attention combine: one wave per (s,b) ----
__global__ __launch_bounds__(256)
void mm_attn_kernel(const bf16_t* __restrict__ Vws,
                    const float* __restrict__ Qws,
                    float* __restrict__ out)
{
    const int wave = threadIdx.x >> 6;
    const int lane = threadIdx.x & 63;
    const int p = blockIdx.x * 4 + wave;
    const int s = p >> 7;
    const int b = p & 127;
    const float*  qrow  = Qws + (size_t)b * A_;
    const bf16_t* vbase = Vws + ((size_t)s * B_ + b) * 3 * A_;

    float4 qv[3];
    bf16x4 vv[3][3];
    float p0 = 0.f, p1 = 0.f, p2 = 0.f;
    #pragma unroll
    for (int j = 0; j < 3; ++j) {
        const int a = lane * 4 + j * 256;
        qv[j]    = *reinterpret_cast<const float4*>(qrow + a);
        vv[0][j] = *reinterpret_cast<const bf16x4*>(vbase + 0*A_ + a);
        vv[1][j] = *reinterpret_cast<const bf16x4*>(vbase + 1*A_ + a);
        vv[2][j] = *reinterpret_cast<const bf16x4*>(vbase + 2*A_ + a);
        p0 += qv[j].x*(float)vv[0][j][0] + qv[j].y*(float)vv[0][j][1]
            + qv[j].z*(float)vv[0][j][2] + qv[j].w*(float)vv[0][j][3];
        p1 += qv[j].x*(float)vv[1][j][0] + qv[j].y*(float)vv[1][j][1]
            + qv[j].z*(float)vv[1][j][2] + qv[j].w*(float)vv[1][j][3];
        p2 += qv[j].x*(float)vv[2][j][0] + qv[j].y*(float)vv[2][j][1]
            + qv[j].z*(float)vv[2][j][2] + qv[j].w*(float)vv[2][j][3];
    }
    #pragma unroll
    for (int d = 1; d < 64; d <<= 1) {
        p0 += __shfl_xor(p0, d);
        p1 += __shfl_xor(p1, d);
        p2 += __shfl_xor(p2, d);
    }
    const float norm = 0.03608439182435161f;   // 1/sqrt(768)
    const float s0 = p0 * norm, s1 = p1 * norm, s2 = p2 * norm;
    const float mx = fmaxf(s0, fmaxf(s1, s2));
    const float e0 = expf(s0 - mx), e1 = expf(s1 - mx), e2 = expf(s2 - mx);
    const float inv = 1.f / (e0 + e1 + e2);
    const float a0 = e0 * inv, a1 = e1 * inv, a2 = e2 * inv;

    float* orow = out + ((size_t)s * B_ + b) * A_;
    #pragma unroll
    for (int j = 0; j < 3; ++j) {
        const int a = lane * 4 + j * 256;
        float4 o;
        o.x = a0*(float)vv[0][j][0] + a1*(float)vv[1][j][0] + a2*(float)vv[2][j][0];
        o.y = a0*(float)vv[0][j][1] + a1*(float)vv[1][j][1] + a2*(float)vv[2][j][1];
        o.z = a0*(float)vv[0][j][2] + a1*(float)vv[1][j][2] + a2*(float)vv[2][j][2];
        o.w = a0*(float)vv[0][j][3] + a1*(float)vv[1][j][3] + a2*(float)vv[2][j][3];
        *reinterpret_cast<float4*>(orow + a) = o;
    }
}

// ============================================================================
// FALLBACK PATH (round-1 GEMM, used only if ws_size is too small)
// ============================================================================
#define LDSPAD 40
__global__ __launch_bounds__(256, 2)
void mm_gemm_kernel(const float* __restrict__ topic,
                    const float* __restrict__ image,
                    const float* __restrict__ text,
                    const float* __restrict__ Wq,
                    const float* __restrict__ bq,
                    const float* __restrict__ Wv,
                    const float* __restrict__ bv,
                    bf16_t* __restrict__ Vws,
                    float*  __restrict__ Qws)
{
    __shared__ bf16_t Alds[128][LDSPAD];
    __shared__ bf16_t Blds[128][LDSPAD];

    const int bid = blockIdx.x;
    const int tid = threadIdx.x;
    const bool isQ = (bid >= S_ * 18);
    int s, tm, tn;
    if (isQ) { s = 0; tm = 0; tn = bid - S_ * 18; }
    else     { s = bid / 18; const int t = bid % 18; tm = t / 6; tn = t % 6; }

    const int ar  = tid >> 1;
    const int aks = (tid & 1) * 16;
    const float* arow;
    if (isQ) {
        arow = topic + (size_t)ar * H_;
    } else {
        const int am  = tm * 128 + ar;
        const int sel = am >> 7;
        const int b   = am & 127;
        if (sel == 0)      arow = topic + (size_t)b * H_;
        else if (sel == 1) arow = image + ((size_t)s * B_ + b) * H_;
        else               arow = text  + ((size_t)s * B_ + b) * H_;
    }
    const int arot = (ar >> 3) & 3;

    const int bn  = tid & 127;
    const int bks = (tid >> 7) * 16;
    const float* wbase = isQ ? Wq : (Wv + (size_t)s * H_ * A_);
    const float* bcolp = wbase + (size_t)(tn * 128 + bn);
    const int brot = (bn >> 3) & 3;

    const int wave = tid >> 6;
    const int lane = tid & 63;
    const int wr = wave >> 1;
    const int wc = wave & 1;
    const int fr = lane & 15;
    const int fg = lane >> 4;

    f32x4 acc[4][4];
    #pragma unroll
    for (int i = 0; i < 4; ++i)
        #pragma unroll
        for (int j = 0; j < 4; ++j)
            acc[i][j] = (f32x4){0.f, 0.f, 0.f, 0.f};

    for (int k0 = 0; k0 < H_; k0 += 32) {
        float4 av[4];
        const float4* ap = reinterpret_cast<const float4*>(arow + k0 + aks);
        #pragma unroll
        for (int i = 0; i < 4; ++i) av[i] = ap[i];
        float bvr[16];
        #pragma unroll
        for (int j = 0; j < 16; ++j) bvr[j] = bcolp[(size_t)(k0 + bks + j) * A_];

        __syncthreads();

        #pragma unroll
        for (int i = 0; i < 4; ++i) {
            const int j = (i + arot) & 3;
            bf16x4 c;
            c[0] = (bf16_t)av[j].x; c[1] = (bf16_t)av[j].y;
            c[2] = (bf16_t)av[j].z; c[3] = (bf16_t)av[j].w;
            *reinterpret_cast<bf16x4*>(&Alds[ar][aks + 4*j]) = c;
        }
        #pragma unroll
        for (int i = 0; i < 4; ++i) {
            const int j = (i + brot) & 3;
            bf16x4 c;
            c[0] = (bf16_t)bvr[4*j+0]; c[1] = (bf16_t)bvr[4*j+1];
            c[2] = (bf16_t)bvr[4*j+2]; c[3] = (bf16_t)bvr[4*j+3];
            *reinterpret_cast<bf16x4*>(&Blds[bn][bks + 4*j]) = c;
        }
        __syncthreads();

        bf16x8 afrag[4], bfrag[4];
        #pragma unroll
        for (int mi = 0; mi < 4; ++mi)
            afrag[mi] = *reinterpret_cast<const bf16x8*>(&Alds[wr*64 + mi*16 + fr][fg*8]);
        #pragma unroll
        for (int ni = 0; ni < 4; ++ni)
            bfrag[ni] = *reinterpret_cast<const bf16x8*>(&Blds[wc*64 + ni*16 + fr][fg*8]);
        #pragma unroll
        for (int mi = 0; mi < 4; ++mi)
            #pragma unroll
            for (int ni = 0; ni < 4; ++ni)
                acc[mi][ni] = __builtin_amdgcn_mfma_f32_16x16x32_bf16(
                    afrag[mi], bfrag[ni], acc[mi][ni], 0, 0, 0);
    }

    if (isQ) {
        #pragma unroll
        for (int ni = 0; ni < 4; ++ni) {
            const int n = tn*128 + wc*64 + ni*16 + fr;
            const float bias = bq[n];
            #pragma unroll
            for (int mi = 0; mi < 4; ++mi)
                #pragma unroll
                for (int j = 0; j < 4; ++j) {
                    const int m = wr*64 + mi*16 + fg*4 + j;
                    Qws[(size_t)m * A_ + n] = acc[mi][ni][j] + bias;
                }
        }
    } else {
        const float* bvrow = bv + (size_t)s * A_;
        #pragma unroll
        for (int ni = 0; ni < 4; ++ni) {
            const int n = tn*128 + wc*64 + ni*16 + fr;
            const float bias = bvrow[n];
            #pragma unroll
            for (int mi = 0; mi < 4; ++mi)
                #pragma unroll
                for (int j = 0; j < 4; ++j) {
                    const int b = wr*64 + mi*16 + fg*4 + j;
                    Vws[(((size_t)s * B_ + b) * 3 + tm) * A_ + n] = (bf16_t)(acc[mi][ni][j] + bias);
                }
        }
    }
}

// ============================================================================
extern "C" void kernel_launch(void* const* d_in, const int* in_sizes, int n_in,
                              void* d_out, int out_size, void* d_ws, size_t ws_size,
                              hipStream_t stream)
{
    const float* topic = (const float*)d_in[0];
    const float* image = (const float*)d_in[1];
    const float* text  = (const float*)d_in[2];
    const float* Wq    = (const float*)d_in[3];
    const float* bq    = (const float*)d_in[4];
    const float* Wv    = (const float*)d_in[5];
    const float* bv    = (const float*)d_in[6];
    float* out = (float*)d_out;

    const size_t szAct = (size_t)(TOPIC_N + 2 * IMG_N) * sizeof(bf16_t);  // 25,362,432
    const size_t szV   = (size_t)S_ * B_ * 3 * A_ * sizeof(bf16_t);       // 37,748,736
    const size_t szQ   = (size_t)B_ * A_ * sizeof(float);                 //    393,216
    const size_t need  = szAct + szV + szQ;                               // ~63.5 MB

    if (ws_size >= need) {
        char* w = (char*)d_ws;
        bf16_t* actB = (bf16_t*)w;  w += szAct;
        bf16_t* Vws  = (bf16_t*)w;  w += szV;
        float*  Qws  = (float*) w;

        convert_kernel<<<(TOPIC_N + 2 * IMG_N) / 8 / 256, 256, 0, stream>>>(topic, image, text, actB);
        gemm_direct<<<2316, 256, 0, stream>>>(Wv, Wq, actB, bq, bv, Vws, Qws);
        mm_attn_kernel<<<S_ * B_ / 4, 256, 0, stream>>>(Vws, Qws, out);
    } else {
        bf16_t* Vws = (bf16_t*)d_ws;
        float*  Qws = (float*)((char*)d_ws + szV);
        mm_gemm_kernel<<<S_ * 18 + 6, 256, 0, stream>>>(topic, image, text, Wq, bq, Wv, bv, Vws, Qws);
        mm_attn_kernel<<<S_ * B_ / 4, 256, 0, stream>>>(Vws, Qws, out);
    }
}

// Round 8
// 110.874 us; speedup vs baseline: 1.0993x; 1.0993x over previous
//
#include <hip/hip_runtime.h>
#include <hip/hip_bf16.h>
#include <math.h>

#define S_ 64
#define B_ 128
#define H_ 768
#define A_ 768

typedef __bf16 bf16_t;
typedef __attribute__((ext_vector_type(8))) __bf16 bf16x8;
typedef __attribute__((ext_vector_type(4))) __bf16 bf16x4;
typedef __attribute__((ext_vector_type(4))) float f32x4;

#define TOPIC_N   98304      // 128*768
#define IMG_N   6291456      // 64*128*768

__device__ __forceinline__ bf16x8 pack8(float4 a, float4 b) {
    bf16x8 o;
    o[0]=(bf16_t)a.x; o[1]=(bf16_t)a.y; o[2]=(bf16_t)a.z; o[3]=(bf16_t)a.w;
    o[4]=(bf16_t)b.x; o[5]=(bf16_t)b.y; o[6]=(bf16_t)b.z; o[7]=(bf16_t)b.w;
    return o;
}

__device__ __forceinline__ void glds16b(const bf16_t* g, bf16_t* l) {
    __builtin_amdgcn_global_load_lds(
        (const __attribute__((address_space(1))) uint32_t*)g,
        (__attribute__((address_space(3))) uint32_t*)l, 16, 0, 0);
}

// ============================================================================
// FAST PATH
// ============================================================================

// ---- prep 1: [topic; image; text] f32 -> bf16, one linear pass ----
__global__ __launch_bounds__(256)
void convert_kernel(const float* __restrict__ topic, const float* __restrict__ image,
                    const float* __restrict__ text, bf16_t* __restrict__ out) {
    const int i = blockIdx.x * 256 + threadIdx.x;      // 8 elems each
    const int T8 = TOPIC_N / 8, I8 = IMG_N / 8;
    const size_t e = (size_t)i * 8;
    const float* src; size_t off;
    if (i < T8)           { src = topic; off = e; }
    else if (i < T8 + I8) { src = image; off = e - TOPIC_N; }
    else                  { src = text;  off = e - TOPIC_N - IMG_N; }
    const float4* p = reinterpret_cast<const float4*>(src + off);
    float4 a = p[0], b = p[1];
    *reinterpret_cast<bf16x8*>(out + e) = pack8(a, b);
}

// ---- prep 2: Wv [s][h][a] f32 -> WT [s][a][h] bf16 (s==64 slab = Wq) ----
__global__ __launch_bounds__(256)
void transpose_kernel(const float* __restrict__ Wv, const float* __restrict__ Wq,
                      bf16_t* __restrict__ WT) {
    __shared__ float Tl[64][65];
    const int bid = blockIdx.x;
    const int s  = bid / 144;
    const int t  = bid % 144;
    const int th = t / 12, ta = t % 12;
    const float* src = (s < S_) ? (Wv + (size_t)s * H_ * A_) : Wq;
    const int tid = threadIdx.x;

    const int r = tid >> 4, c = (tid & 15) * 4;
    #pragma unroll
    for (int i = 0; i < 4; ++i) {
        const int row = i * 16 + r;
        float4 v = *reinterpret_cast<const float4*>(src + (size_t)(th*64 + row) * A_ + ta*64 + c);
        Tl[row][c+0] = v.x; Tl[row][c+1] = v.y; Tl[row][c+2] = v.z; Tl[row][c+3] = v.w;
    }
    __syncthreads();
    bf16_t* dstbase = WT + (size_t)s * A_ * H_ + (size_t)th * 64;
    #pragma unroll
    for (int i = 0; i < 2; ++i) {
        const int ch = tid + i * 256;
        const int a = ch >> 3, hc = ch & 7;
        bf16x8 o;
        #pragma unroll
        for (int j = 0; j < 8; ++j) o[j] = (bf16_t)Tl[hc*8 + j][a];
        *reinterpret_cast<bf16x8*>(dstbase + (size_t)(ta*64 + a) * H_ + hc*8) = o;
    }
}

// ---- main GEMM: BM=128 x BN=192 tile, BK=64, 512 thr (8 waves, 2M x 4N).
//      Both operands bf16 k-contiguous, glds-staged with both-sides XOR
//      chunk-swizzle (c ^= row&7; inverse on global source, rule #21).
//      2-phase pipeline (T3-minimum): stage(t+1) issued BEFORE frag-read+MFMA,
//      one vmcnt(0)+lgkmcnt(0)+s_barrier per iter. 80 KB LDS -> 2 blocks/CU.
//      Per wave 64x48 output: 24 MFMA per K-step. Grid 772 = 3.02/CU. ----
__global__ __launch_bounds__(512, 4)
void gemm_big(const bf16_t* __restrict__ WT, const bf16_t* __restrict__ actB,
              const float* __restrict__ bq, const float* __restrict__ bv,
              bf16_t* __restrict__ Vws, float* __restrict__ Qws)
{
    __shared__ bf16_t Al[2][128 * 64];   // 16 KB each
    __shared__ bf16_t Bl[2][192 * 64];   // 24 KB each

    // XCD-chunked bijective remap, nwg = 772 (q=96, r=4) [T1/m204]
    const int b0 = blockIdx.x;
    const int xcd = b0 & 7, ii = b0 >> 3;
    const int bid = (xcd < 4) ? (xcd * 97 + ii) : (388 + (xcd - 4) * 96 + ii);

    const int tid = threadIdx.x;
    const bool isQ = (bid >= 768);
    int s, tm, tn;
    if (isQ) { s = S_; tm = 0; tn = bid - 768; }
    else     { s = bid / 12; const int t = bid % 12; tm = t / 4; tn = t % 4; }

    const bf16_t* Apanel;
    if (isQ || tm == 0) Apanel = actB;
    else if (tm == 1)   Apanel = actB + TOPIC_N + (size_t)s * B_ * H_;
    else                Apanel = actB + TOPIC_N + IMG_N + (size_t)s * B_ * H_;
    const bf16_t* Bbase = WT + (size_t)s * A_ * H_ + (size_t)(tn * 192) * H_;

    const int wv = tid >> 6, lane = tid & 63;
    const int wr = wv >> 2, wc = wv & 3;          // wave tile: 64 rows x 48 cols
    const int fr = lane & 15, fg = lane >> 4;
    const int fx = fr & 7;

    f32x4 acc[4][3];
    #pragma unroll
    for (int i = 0; i < 4; ++i)
        #pragma unroll
        for (int j = 0; j < 3; ++j)
            acc[i][j] = (f32x4){0.f, 0.f, 0.f, 0.f};

    // stage K-step t1 into buffer buf: 5 glds per thread, zero reg consumers
    auto stage = [&](int t1, int buf) {
        const int k0 = t1 * 64;
        #pragma unroll
        for (int q = 0; q < 2; ++q) {              // A: 128 rows x 8 chunks
            const int slot = (q * 8 + wv) * 64 + lane;
            const int row = slot >> 3, c = slot & 7;
            glds16b(Apanel + (size_t)row * H_ + k0 + ((c ^ (row & 7)) * 8),
                    &Al[buf][(q * 8 + wv) * 512]);
        }
        #pragma unroll
        for (int q = 0; q < 3; ++q) {              // B: 192 rows x 8 chunks
            const int slot = (q * 8 + wv) * 64 + lane;
            const int row = slot >> 3, c = slot & 7;
            glds16b(Bbase + (size_t)row * H_ + k0 + ((c ^ (row & 7)) * 8),
                    &Bl[buf][(q * 8 + wv) * 512]);
        }
    };

    stage(0, 0);
    asm volatile("s_waitcnt vmcnt(0)" ::: "memory");
    __builtin_amdgcn_sched_barrier(0);
    __builtin_amdgcn_s_barrier();
    __builtin_amdgcn_sched_barrier(0);

    #pragma unroll
    for (int t = 0; t < 12; ++t) {
        const int cur = t & 1;
        if (t < 11) stage(t + 1, cur ^ 1);         // prefetch flies under compute
        __builtin_amdgcn_sched_barrier(0);

        #pragma unroll
        for (int kk = 0; kk < 2; ++kk) {
            bf16x8 af[4], bf_[3];
            const int ch = ((kk * 4 + fg) ^ fx) * 8;
            #pragma unroll
            for (int mi = 0; mi < 4; ++mi)
                af[mi] = *reinterpret_cast<const bf16x8*>(
                    &Al[cur][(wr * 64 + mi * 16 + fr) * 64 + ch]);
            #pragma unroll
            for (int ni = 0; ni < 3; ++ni)
                bf_[ni] = *reinterpret_cast<const bf16x8*>(
                    &Bl[cur][(wc * 48 + ni * 16 + fr) * 64 + ch]);
            #pragma unroll
            for (int mi = 0; mi < 4; ++mi)
                #pragma unroll
                for (int ni = 0; ni < 3; ++ni)
                    acc[mi][ni] = __builtin_amdgcn_mfma_f32_16x16x32_bf16(
                        af[mi], bf_[ni], acc[mi][ni], 0, 0, 0);
        }

        if (t < 11) {
            asm volatile("s_waitcnt vmcnt(0) lgkmcnt(0)" ::: "memory");
            __builtin_amdgcn_sched_barrier(0);
            __builtin_amdgcn_s_barrier();
            __builtin_amdgcn_sched_barrier(0);
        }
    }

    // ---- epilogue: C/D map col = lane&15, row = (lane>>4)*4 + j ----
    if (isQ) {
        #pragma unroll
        for (int ni = 0; ni < 3; ++ni) {
            const int n = tn * 192 + wc * 48 + ni * 16 + fr;
            const float bias = bq[n];
            #pragma unroll
            for (int mi = 0; mi < 4; ++mi)
                #pragma unroll
                for (int j = 0; j < 4; ++j) {
                    const int m = wr * 64 + mi * 16 + fg * 4 + j;
                    Qws[(size_t)m * A_ + n] = acc[mi][ni][j] + bias;
                }
        }
    } else {
        const float* bvrow = bv + (size_t)s * A_;
        #pragma unroll
        for (int ni = 0; ni < 3; ++ni) {
            const int n = tn * 192 + wc * 48 + ni * 16 + fr;
            const float bias = bvrow[n];
            #pragma unroll
            for (int mi = 0; mi < 4; ++mi)
                #pragma unroll
                for (int j = 0; j < 4; ++j) {
                    const int b = wr * 64 + mi * 16 + fg * 4 + j;
                    Vws[(((size_t)s * B_ + b) * 3 + tm) * A_ + n] = (bf16_t)(acc[mi][ni][j] + bias);
                }
        }
    }
}

// ---- attention combine: one wave per (s,b) ----
__global__ __launch_bounds__(256)
void mm_attn_kernel(const bf16_t* __restrict__ Vws,
                    const float* __restrict__ Qws,
                    float* __restrict__ out)
{
    const int wave = threadIdx.x >> 6;
    const int lane = threadIdx.x & 63;
    const int p = blockIdx.x * 4 + wave;
    const int s = p >> 7;
    const int b = p & 127;
    const float*  qrow  = Qws + (size_t)b * A_;
    const bf16_t* vbase = Vws + ((size_t)s * B_ + b) * 3 * A_;

    float4 qv[3];
    bf16x4 vv[3][3];
    float p0 = 0.f, p1 = 0.f, p2 = 0.f;
    #pragma unroll
    for (int j = 0; j < 3; ++j) {
        const int a = lane * 4 + j * 256;
        qv[j]    = *reinterpret_cast<const float4*>(qrow + a);
        vv[0][j] = *reinterpret_cast<const bf16x4*>(vbase + 0*A_ + a);
        vv[1][j] = *reinterpret_cast<const bf16x4*>(vbase + 1*A_ + a);
        vv[2][j] = *reinterpret_cast<const bf16x4*>(vbase + 2*A_ + a);
        p0 += qv[j].x*(float)vv[0][j][0] + qv[j].y*(float)vv[0][j][1]
            + qv[j].z*(float)vv[0][j][2] + qv[j].w*(float)vv[0][j][3];
        p1 += qv[j].x*(float)vv[1][j][0] + qv[j].y*(float)vv[1][j][1]
            + qv[j].z*(float)vv[1][j][2] + qv[j].w*(float)vv[1][j][3];
        p2 += qv[j].x*(float)vv[2][j][0] + qv[j].y*(float)vv[2][j][1]
            + qv[j].z*(float)vv[2][j][2] + qv[j].w*(float)vv[2][j][3];
    }
    #pragma unroll
    for (int d = 1; d < 64; d <<= 1) {
        p0 += __shfl_xor(p0, d);
        p1 += __shfl_xor(p1, d);
        p2 += __shfl_xor(p2, d);
    }
    const float norm = 0.03608439182435161f;   // 1/sqrt(768)
    const float s0 = p0 * norm, s1 = p1 * norm, s2 = p2 * norm;
    const float mx = fmaxf(s0, fmaxf(s1, s2));
    const float e0 = expf(s0 - mx), e1 = expf(s1 - mx), e2 = expf(s2 - mx);
    const float inv = 1.f / (e0 + e1 + e2);
    const float a0 = e0 * inv, a1 = e1 * inv, a2 = e2 * inv;

    float* orow = out + ((size_t)s * B_ + b) * A_;
    #pragma unroll
    for (int j = 0; j < 3; ++j) {
        const int a = lane * 4 + j * 256;
        float4 o;
        o.x = a0*(float)vv[0][j][0] + a1*(float)vv[1][j][0] + a2*(float)vv[2][j][0];
        o.y = a0*(float)vv[0][j][1] + a1*(float)vv[1][j][1] + a2*(float)vv[2][j][1];
        o.z = a0*(float)vv[0][j][2] + a1*(float)vv[1][j][2] + a2*(float)vv[2][j][2];
        o.w = a0*(float)vv[0][j][3] + a1*(float)vv[1][j][3] + a2*(float)vv[2][j][3];
        *reinterpret_cast<float4*>(orow + a) = o;
    }
}

// ============================================================================
// FALLBACK PATH (round-1 GEMM, used only if ws_size is too small)
// ============================================================================
#define LDSPAD 40
__global__ __launch_bounds__(256, 2)
void mm_gemm_kernel(const float* __restrict__ topic,
                    const float* __restrict__ image,
                    const float* __restrict__ text,
                    const float* __restrict__ Wq,
                    const float* __restrict__ bq,
                    const float* __restrict__ Wv,
                    const float* __restrict__ bv,
                    bf16_t* __restrict__ Vws,
                    float*  __restrict__ Qws)
{
    __shared__ bf16_t Alds[128][LDSPAD];
    __shared__ bf16_t Blds[128][LDSPAD];

    const int bid = blockIdx.x;
    const int tid = threadIdx.x;
    const bool isQ = (bid >= S_ * 18);
    int s, tm, tn;
    if (isQ) { s = 0; tm = 0; tn = bid - S_ * 18; }
    else     { s = bid / 18; const int t = bid % 18; tm = t / 6; tn = t % 6; }

    const int ar  = tid >> 1;
    const int aks = (tid & 1) * 16;
    const float* arow;
    if (isQ) {
        arow = topic + (size_t)ar * H_;
    } else {
        const int am  = tm * 128 + ar;
        const int sel = am >> 7;
        const int b   = am & 127;
        if (sel == 0)      arow = topic + (size_t)b * H_;
        else if (sel == 1) arow = image + ((size_t)s * B_ + b) * H_;
        else               arow = text  + ((size_t)s * B_ + b) * H_;
    }
    const int arot = (ar >> 3) & 3;

    const int bn  = tid & 127;
    const int bks = (tid >> 7) * 16;
    const float* wbase = isQ ? Wq : (Wv + (size_t)s * H_ * A_);
    const float* bcolp = wbase + (size_t)(tn * 128 + bn);
    const int brot = (bn >> 3) & 3;

    const int wave = tid >> 6;
    const int lane = tid & 63;
    const int wr = wave >> 1;
    const int wc = wave & 1;
    const int fr = lane & 15;
    const int fg = lane >> 4;

    f32x4 acc[4][4];
    #pragma unroll
    for (int i = 0; i < 4; ++i)
        #pragma unroll
        for (int j = 0; j < 4; ++j)
            acc[i][j] = (f32x4){0.f, 0.f, 0.f, 0.f};

    for (int k0 = 0; k0 < H_; k0 += 32) {
        float4 av[4];
        const float4* ap = reinterpret_cast<const float4*>(arow + k0 + aks);
        #pragma unroll
        for (int i = 0; i < 4; ++i) av[i] = ap[i];
        float bvr[16];
        #pragma unroll
        for (int j = 0; j < 16; ++j) bvr[j] = bcolp[(size_t)(k0 + bks + j) * A_];

        __syncthreads();

        #pragma unroll
        for (int i = 0; i < 4; ++i) {
            const int j = (i + arot) & 3;
            bf16x4 c;
            c[0] = (bf16_t)av[j].x; c[1] = (bf16_t)av[j].y;
            c[2] = (bf16_t)av[j].z; c[3] = (bf16_t)av[j].w;
            *reinterpret_cast<bf16x4*>(&Alds[ar][aks + 4*j]) = c;
        }
        #pragma unroll
        for (int i = 0; i < 4; ++i) {
            const int j = (i + brot) & 3;
            bf16x4 c;
            c[0] = (bf16_t)bvr[4*j+0]; c[1] = (bf16_t)bvr[4*j+1];
            c[2] = (bf16_t)bvr[4*j+2]; c[3] = (bf16_t)bvr[4*j+3];
            *reinterpret_cast<bf16x4*>(&Blds[bn][bks + 4*j]) = c;
        }
        __syncthreads();

        bf16x8 afrag[4], bfrag[4];
        #pragma unroll
        for (int mi = 0; mi < 4; ++mi)
            afrag[mi] = *reinterpret_cast<const bf16x8*>(&Alds[wr*64 + mi*16 + fr][fg*8]);
        #pragma unroll
        for (int ni = 0; ni < 4; ++ni)
            bfrag[ni] = *reinterpret_cast<const bf16x8*>(&Blds[wc*64 + ni*16 + fr][fg*8]);
        #pragma unroll
        for (int mi = 0; mi < 4; ++mi)
            #pragma unroll
            for (int ni = 0; ni < 4; ++ni)
                acc[mi][ni] = __builtin_amdgcn_mfma_f32_16x16x32_bf16(
                    afrag[mi], bfrag[ni], acc[mi][ni], 0, 0, 0);
    }

    if (isQ) {
        #pragma unroll
        for (int ni = 0; ni < 4; ++ni) {
            const int n = tn*128 + wc*64 + ni*16 + fr;
            const float bias = bq[n];
            #pragma unroll
            for (int mi = 0; mi < 4; ++mi)
                #pragma unroll
                for (int j = 0; j < 4; ++j) {
                    const int m = wr*64 + mi*16 + fg*4 + j;
                    Qws[(size_t)m * A_ + n] = acc[mi][ni][j] + bias;
                }
        }
    } else {
        const float* bvrow = bv + (size_t)s * A_;
        #pragma unroll
        for (int ni = 0; ni < 4; ++ni) {
            const int n = tn*128 + wc*64 + ni*16 + fr;
            const float bias = bvrow[n];
            #pragma unroll
            for (int mi = 0; mi < 4; ++mi)
                #pragma unroll
                for (int j = 0; j < 4; ++j) {
                    const int b = wr*64 + mi*16 + fg*4 + j;
                    Vws[(((size_t)s * B_ + b) * 3 + tm) * A_ + n] = (bf16_t)(acc[mi][ni][j] + bias);
                }
        }
    }
}

// ============================================================================
extern "C" void kernel_launch(void* const* d_in, const int* in_sizes, int n_in,
                              void* d_out, int out_size, void* d_ws, size_t ws_size,
                              hipStream_t stream)
{
    const float* topic = (const float*)d_in[0];
    const float* image = (const float*)d_in[1];
    const float* text  = (const float*)d_in[2];
    const float* Wq    = (const float*)d_in[3];
    const float* bq    = (const float*)d_in[4];
    const float* Wv    = (const float*)d_in[5];
    const float* bv    = (const float*)d_in[6];
    float* out = (float*)d_out;

    const size_t szWT  = (size_t)(S_ + 1) * A_ * H_ * sizeof(bf16_t);     // 76,677,120
    const size_t szAct = (size_t)(TOPIC_N + 2 * IMG_N) * sizeof(bf16_t);  // 25,362,432
    const size_t szV   = (size_t)S_ * B_ * 3 * A_ * sizeof(bf16_t);       // 37,748,736
    const size_t szQ   = (size_t)B_ * A_ * sizeof(float);                 //    393,216
    const size_t need  = szWT + szAct + szV + szQ;                        // ~140.2 MB

    if (ws_size >= need) {
        char* w = (char*)d_ws;
        bf16_t* WT   = (bf16_t*)w;  w += szWT;
        bf16_t* actB = (bf16_t*)w;  w += szAct;
        bf16_t* Vws  = (bf16_t*)w;  w += szV;
        float*  Qws  = (float*) w;

        convert_kernel<<<(TOPIC_N + 2 * IMG_N) / 8 / 256, 256, 0, stream>>>(topic, image, text, actB);
        transpose_kernel<<<(S_ + 1) * 144, 256, 0, stream>>>(Wv, Wq, WT);
        gemm_big<<<772, 512, 0, stream>>>(WT, actB, bq, bv, Vws, Qws);
        mm_attn_kernel<<<S_ * B_ / 4, 256, 0, stream>>>(Vws, Qws, out);
    } else {
        bf16_t* Vws = (bf16_t*)d_ws;
        float*  Qws = (float*)((char*)d_ws + szV);
        mm_gemm_kernel<<<S_ * 18 + 6, 256, 0, stream>>>(topic, image, text, Wq, bq, Wv, bv, Vws, Qws);
        mm_attn_kernel<<<S_ * B_ / 4, 256, 0, stream>>>(Vws, Qws, out);
    }
}

// Round 9
// 92.150 us; speedup vs baseline: 1.3226x; 1.2032x over previous
//
#include <hip/hip_runtime.h>
#include <hip/hip_bf16.h>
#include <math.h>

#define S_ 64
#define B_ 128
#define H_ 768
#define A_ 768

typedef __bf16 bf16_t;
typedef __attribute__((ext_vector_type(8))) __bf16 bf16x8;
typedef __attribute__((ext_vector_type(4))) __bf16 bf16x4;
typedef __attribute__((ext_vector_type(2))) __bf16 bf16x2;
typedef __attribute__((ext_vector_type(4))) float f32x4;

#define TOPIC_N   98304      // 128*768
#define IMG_N   6291456      // 64*128*768

__device__ __forceinline__ bf16x8 pack8(float4 a, float4 b) {
    bf16x8 o;
    o[0]=(bf16_t)a.x; o[1]=(bf16_t)a.y; o[2]=(bf16_t)a.z; o[3]=(bf16_t)a.w;
    o[4]=(bf16_t)b.x; o[5]=(bf16_t)b.y; o[6]=(bf16_t)b.z; o[7]=(bf16_t)b.w;
    return o;
}

__device__ __forceinline__ void glds16b(const bf16_t* g, bf16_t* l) {
    __builtin_amdgcn_global_load_lds(
        (const __attribute__((address_space(1))) uint32_t*)g,
        (__attribute__((address_space(3))) uint32_t*)l, 16, 0, 0);
}

// ============================================================================
// FAST PATH
// ============================================================================

// ---- prep: [topic; image; text] f32 -> bf16, one linear pass ----
__global__ __launch_bounds__(256)
void convert_kernel(const float* __restrict__ topic, const float* __restrict__ image,
                    const float* __restrict__ text, bf16_t* __restrict__ out) {
    const int i = blockIdx.x * 256 + threadIdx.x;      // 8 elems each
    const int T8 = TOPIC_N / 8, I8 = IMG_N / 8;
    const size_t e = (size_t)i * 8;
    const float* src; size_t off;
    if (i < T8)           { src = topic; off = e; }
    else if (i < T8 + I8) { src = image; off = e - TOPIC_N; }
    else                  { src = text;  off = e - TOPIC_N - IMG_N; }
    const float4* p = reinterpret_cast<const float4*>(src + off);
    float4 a = p[0], b = p[1];
    *reinterpret_cast<bf16x8*>(out + e) = pack8(a, b);
}

// ---- fused GEMM: BM=128 x BN=192, BK=64, 512 thr (8 waves, 2M x 4N).
//      W read f32 [k][n] DIRECTLY from HBM (no transpose pass): 6 dwordx4 /
//      thread held in regs across the MFMA cluster (T14 async-split; loads
//      pinned early by sched_barrier), then cvt + in-reg 2x4 transpose ->
//      12 b32 writes into Bl[n][k] with involution key (n>>3)&7 (writes
//      2-way = free; b128 frag reads conflict-free). A bf16 via glds with
//      r8's proven XOR chunk swizzle. One s_barrier per K-step.
//      80 KB LDS -> 2 blocks/CU; 24 MFMA/wave/K-step. Grid 772. ----
__global__ __launch_bounds__(512, 4)
void gemm_fused(const float* __restrict__ Wv, const float* __restrict__ Wq,
                const bf16_t* __restrict__ actB,
                const float* __restrict__ bq, const float* __restrict__ bv,
                bf16_t* __restrict__ Vws, float* __restrict__ Qws)
{
    __shared__ bf16_t Al[2][128 * 64];   // 16 KB each
    __shared__ bf16_t Bl[2][192 * 64];   // 24 KB each

    // XCD-chunked bijective remap, nwg = 772 (q=96, r=4) [T1/m204]
    const int b0 = blockIdx.x;
    const int xcd = b0 & 7, ii = b0 >> 3;
    const int bid = (xcd < 4) ? (xcd * 97 + ii) : (388 + (xcd - 4) * 96 + ii);

    const int tid = threadIdx.x;
    const bool isQ = (bid >= 768);
    int s, tm, tn;
    if (isQ) { s = S_; tm = 0; tn = bid - 768; }
    else     { s = bid / 12; const int t = bid % 12; tm = t / 4; tn = t % 4; }

    const bf16_t* Apanel;
    if (isQ || tm == 0) Apanel = actB;
    else if (tm == 1)   Apanel = actB + TOPIC_N + (size_t)s * B_ * H_;
    else                Apanel = actB + TOPIC_N + IMG_N + (size_t)s * B_ * H_;
    const float* Wbase = (isQ ? Wq : (Wv + (size_t)s * H_ * A_)) + tn * 192;

    const int wv = tid >> 6, lane = tid & 63;
    const int wr = wv >> 2, wc = wv & 3;          // wave tile: 64 rows x 48 cols
    const int fr = lane & 15, fg = lane >> 4;

    // W staging thread mapping: k-pair wk0 = 2*(tid>>4), n-groups 4*(tid&15)+64j
    const int wp  = tid >> 4;                      // 0..31
    const int wg  = tid & 15;
    const int wk0 = 2 * wp;

    f32x4 acc[4][3];
    #pragma unroll
    for (int i = 0; i < 4; ++i)
        #pragma unroll
        for (int j = 0; j < 3; ++j)
            acc[i][j] = (f32x4){0.f, 0.f, 0.f, 0.f};

    // A: 2 glds per thread, pre-swizzled source (r8 verbatim)
    auto stageA = [&](int t1, int buf) {
        const int k0 = t1 * 64;
        #pragma unroll
        for (int q = 0; q < 2; ++q) {
            const int slot = (q * 8 + wv) * 64 + lane;
            const int row = slot >> 3, c = slot & 7;
            glds16b(Apanel + (size_t)row * H_ + k0 + ((c ^ (row & 7)) * 8),
                    &Al[buf][(q * 8 + wv) * 512]);
        }
    };

    // W: 6 coalesced dwordx4 into regs (2 k-rows x 12 n's)
    f32x4 wreg[6];
    auto loadW = [&](int t1) {
        const float* base = Wbase + (size_t)(t1 * 64 + wk0) * A_;
        #pragma unroll
        for (int j = 0; j < 3; ++j) {
            wreg[2*j]   = *reinterpret_cast<const f32x4*>(base +        wg * 4 + 64 * j);
            wreg[2*j+1] = *reinterpret_cast<const f32x4*>(base + A_ +   wg * 4 + 64 * j);
        }
    };
    // cvt + in-reg transpose -> Bl[n][k] swizzled (key (n>>3)&7; 2-way writes)
    auto writeB = [&](int buf) {
        #pragma unroll
        for (int j = 0; j < 3; ++j)
            #pragma unroll
            for (int i = 0; i < 4; ++i) {
                const int n  = wg * 4 + 64 * j + i;
                const int kx = (((wk0 >> 3) ^ ((n >> 3) & 7)) << 3) + (wk0 & 7);
                bf16x2 pr;
                pr[0] = (bf16_t)wreg[2*j][i];
                pr[1] = (bf16_t)wreg[2*j+1][i];
                *reinterpret_cast<bf16x2*>(&Bl[buf][n * 64 + kx]) = pr;
            }
    };

    // ---- prologue: tile 0 ----
    loadW(0);
    stageA(0, 0);
    writeB(0);                                   // auto vmcnt for wreg
    asm volatile("s_waitcnt vmcnt(0) lgkmcnt(0)" ::: "memory");
    __builtin_amdgcn_sched_barrier(0);
    __builtin_amdgcn_s_barrier();
    __builtin_amdgcn_sched_barrier(0);

    #pragma unroll
    for (int t = 0; t < 12; ++t) {
        const int cur = t & 1, nxt = cur ^ 1;
        if (t < 11) {
            loadW(t + 1);                        // oldest in vm queue
            stageA(t + 1, nxt);                  // newest (stays in flight longer)
        }
        __builtin_amdgcn_sched_barrier(0);       // pin loads above the compute

        #pragma unroll
        for (int kk = 0; kk < 2; ++kk) {
            bf16x8 af[4], bf_[3];
            const int kb = kk * 4 + fg;
            #pragma unroll
            for (int mi = 0; mi < 4; ++mi) {
                const int m = wr * 64 + mi * 16 + fr;
                af[mi] = *reinterpret_cast<const bf16x8*>(
                    &Al[cur][m * 64 + ((kb ^ (m & 7)) << 3)]);
            }
            #pragma unroll
            for (int ni = 0; ni < 3; ++ni) {
                const int n = wc * 48 + ni * 16 + fr;
                bf_[ni] = *reinterpret_cast<const bf16x8*>(
                    &Bl[cur][n * 64 + ((kb ^ ((n >> 3) & 7)) << 3)]);
            }
            #pragma unroll
            for (int mi = 0; mi < 4; ++mi)
                #pragma unroll
                for (int ni = 0; ni < 3; ++ni)
                    acc[mi][ni] = __builtin_amdgcn_mfma_f32_16x16x32_bf16(
                        af[mi], bf_[ni], acc[mi][ni], 0, 0, 0);
        }
        __builtin_amdgcn_sched_barrier(0);

        if (t < 11) {
            writeB(nxt);                         // compiler waits vmcnt(2): W only
            asm volatile("s_waitcnt vmcnt(0) lgkmcnt(0)" ::: "memory");
            __builtin_amdgcn_sched_barrier(0);
            __builtin_amdgcn_s_barrier();
            __builtin_amdgcn_sched_barrier(0);
        }
    }

    // ---- epilogue: C/D map col = lane&15, row = (lane>>4)*4 + j ----
    if (isQ) {
        #pragma unroll
        for (int ni = 0; ni < 3; ++ni) {
            const int n = tn * 192 + wc * 48 + ni * 16 + fr;
            const float bias = bq[n];
            #pragma unroll
            for (int mi = 0; mi < 4; ++mi)
                #pragma unroll
                for (int j = 0; j < 4; ++j) {
                    const int m = wr * 64 + mi * 16 + fg * 4 + j;
                    Qws[(size_t)m * A_ + n] = acc[mi][ni][j] + bias;
                }
        }
    } else {
        const float* bvrow = bv + (size_t)s * A_;
        #pragma unroll
        for (int ni = 0; ni < 3; ++ni) {
            const int n = tn * 192 + wc * 48 + ni * 16 + fr;
            const float bias = bvrow[n];
            #pragma unroll
            for (int mi = 0; mi < 4; ++mi)
                #pragma unroll
                for (int j = 0; j < 4; ++j) {
                    const int b = wr * 64 + mi * 16 + fg * 4 + j;
                    Vws[(((size_t)s * B_ + b) * 3 + tm) * A_ + n] = (bf16_t)(acc[mi][ni][j] + bias);
                }
        }
    }
}

// ---- attention combine: one wave per (s,b) ----
__global__ __launch_bounds__(256)
void mm_attn_kernel(const bf16_t* __restrict__ Vws,
                    const float* __restrict__ Qws,
                    float* __restrict__ out)
{
    const int wave = threadIdx.x >> 6;
    const int lane = threadIdx.x & 63;
    const int p = blockIdx.x * 4 + wave;
    const int s = p >> 7;
    const int b = p & 127;
    const float*  qrow  = Qws + (size_t)b * A_;
    const bf16_t* vbase = Vws + ((size_t)s * B_ + b) * 3 * A_;

    float4 qv[3];
    bf16x4 vv[3][3];
    float p0 = 0.f, p1 = 0.f, p2 = 0.f;
    #pragma unroll
    for (int j = 0; j < 3; ++j) {
        const int a = lane * 4 + j * 256;
        qv[j]    = *reinterpret_cast<const float4*>(qrow + a);
        vv[0][j] = *reinterpret_cast<const bf16x4*>(vbase + 0*A_ + a);
        vv[1][j] = *reinterpret_cast<const bf16x4*>(vbase + 1*A_ + a);
        vv[2][j] = *reinterpret_cast<const bf16x4*>(vbase + 2*A_ + a);
        p0 += qv[j].x*(float)vv[0][j][0] + qv[j].y*(float)vv[0][j][1]
            + qv[j].z*(float)vv[0][j][2] + qv[j].w*(float)vv[0][j][3];
        p1 += qv[j].x*(float)vv[1][j][0] + qv[j].y*(float)vv[1][j][1]
            + qv[j].z*(float)vv[1][j][2] + qv[j].w*(float)vv[1][j][3];
        p2 += qv[j].x*(float)vv[2][j][0] + qv[j].y*(float)vv[2][j][1]
            + qv[j].z*(float)vv[2][j][2] + qv[j].w*(float)vv[2][j][3];
    }
    #pragma unroll
    for (int d = 1; d < 64; d <<= 1) {
        p0 += __shfl_xor(p0, d);
        p1 += __shfl_xor(p1, d);
        p2 += __shfl_xor(p2, d);
    }
    const float norm = 0.03608439182435161f;   // 1/sqrt(768)
    const float s0 = p0 * norm, s1 = p1 * norm, s2 = p2 * norm;
    const float mx = fmaxf(s0, fmaxf(s1, s2));
    const float e0 = expf(s0 - mx), e1 = expf(s1 - mx), e2 = expf(s2 - mx);
    const float inv = 1.f / (e0 + e1 + e2);
    const float a0 = e0 * inv, a1 = e1 * inv, a2 = e2 * inv;

    float* orow = out + ((size_t)s * B_ + b) * A_;
    #pragma unroll
    for (int j = 0; j < 3; ++j) {
        const int a = lane * 4 + j * 256;
        float4 o;
        o.x = a0*(float)vv[0][j][0] + a1*(float)vv[1][j][0] + a2*(float)vv[2][j][0];
        o.y = a0*(float)vv[0][j][1] + a1*(float)vv[1][j][1] + a2*(float)vv[2][j][1];
        o.z = a0*(float)vv[0][j][2] + a1*(float)vv[1][j][2] + a2*(float)vv[2][j][2];
        o.w = a0*(float)vv[0][j][3] + a1*(float)vv[1][j][3] + a2*(float)vv[2][j][3];
        *reinterpret_cast<float4*>(orow + a) = o;
    }
}

// ============================================================================
// FALLBACK PATH (round-1 GEMM, used only if ws_size is too small)
// ============================================================================
#define LDSPAD 40
__global__ __launch_bounds__(256, 2)
void mm_gemm_kernel(const float* __restrict__ topic,
                    const float* __restrict__ image,
                    const float* __restrict__ text,
                    const float* __restrict__ Wq,
                    const float* __restrict__ bq,
                    const float* __restrict__ Wv,
                    const float* __restrict__ bv,
                    bf16_t* __restrict__ Vws,
                    float*  __restrict__ Qws)
{
    __shared__ bf16_t Alds[128][LDSPAD];
    __shared__ bf16_t Blds[128][LDSPAD];

    const int bid = blockIdx.x;
    const int tid = threadIdx.x;
    const bool isQ = (bid >= S_ * 18);
    int s, tm, tn;
    if (isQ) { s = 0; tm = 0; tn = bid - S_ * 18; }
    else     { s = bid / 18; const int t = bid % 18; tm = t / 6; tn = t % 6; }

    const int ar  = tid >> 1;
    const int aks = (tid & 1) * 16;
    const float* arow;
    if (isQ) {
        arow = topic + (size_t)ar * H_;
    } else {
        const int am  = tm * 128 + ar;
        const int sel = am >> 7;
        const int b   = am & 127;
        if (sel == 0)      arow = topic + (size_t)b * H_;
        else if (sel == 1) arow = image + ((size_t)s * B_ + b) * H_;
        else               arow = text  + ((size_t)s * B_ + b) * H_;
    }
    const int arot = (ar >> 3) & 3;

    const int bn  = tid & 127;
    const int bks = (tid >> 7) * 16;
    const float* wbase = isQ ? Wq : (Wv + (size_t)s * H_ * A_);
    const float* bcolp = wbase + (size_t)(tn * 128 + bn);
    const int brot = (bn >> 3) & 3;

    const int wave = tid >> 6;
    const int lane = tid & 63;
    const int wr = wave >> 1;
    const int wc = wave & 1;
    const int fr = lane & 15;
    const int fg = lane >> 4;

    f32x4 acc[4][4];
    #pragma unroll
    for (int i = 0; i < 4; ++i)
        #pragma unroll
        for (int j = 0; j < 4; ++j)
            acc[i][j] = (f32x4){0.f, 0.f, 0.f, 0.f};

    for (int k0 = 0; k0 < H_; k0 += 32) {
        float4 av[4];
        const float4* ap = reinterpret_cast<const float4*>(arow + k0 + aks);
        #pragma unroll
        for (int i = 0; i < 4; ++i) av[i] = ap[i];
        float bvr[16];
        #pragma unroll
        for (int j = 0; j < 16; ++j) bvr[j] = bcolp[(size_t)(k0 + bks + j) * A_];

        __syncthreads();

        #pragma unroll
        for (int i = 0; i < 4; ++i) {
            const int j = (i + arot) & 3;
            bf16x4 c;
            c[0] = (bf16_t)av[j].x; c[1] = (bf16_t)av[j].y;
            c[2] = (bf16_t)av[j].z; c[3] = (bf16_t)av[j].w;
            *reinterpret_cast<bf16x4*>(&Alds[ar][aks + 4*j]) = c;
        }
        #pragma unroll
        for (int i = 0; i < 4; ++i) {
            const int j = (i + brot) & 3;
            bf16x4 c;
            c[0] = (bf16_t)bvr[4*j+0]; c[1] = (bf16_t)bvr[4*j+1];
            c[2] = (bf16_t)bvr[4*j+2]; c[3] = (bf16_t)bvr[4*j+3];
            *reinterpret_cast<bf16x4*>(&Blds[bn][bks + 4*j]) = c;
        }
        __syncthreads();

        bf16x8 afrag[4], bfrag[4];
        #pragma unroll
        for (int mi = 0; mi < 4; ++mi)
            afrag[mi] = *reinterpret_cast<const bf16x8*>(&Alds[wr*64 + mi*16 + fr][fg*8]);
        #pragma unroll
        for (int ni = 0; ni < 4; ++ni)
            bfrag[ni] = *reinterpret_cast<const bf16x8*>(&Blds[wc*64 + ni*16 + fr][fg*8]);
        #pragma unroll
        for (int mi = 0; mi < 4; ++mi)
            #pragma unroll
            for (int ni = 0; ni < 4; ++ni)
                acc[mi][ni] = __builtin_amdgcn_mfma_f32_16x16x32_bf16(
                    afrag[mi], bfrag[ni], acc[mi][ni], 0, 0, 0);
    }

    if (isQ) {
        #pragma unroll
        for (int ni = 0; ni < 4; ++ni) {
            const int n = tn*128 + wc*64 + ni*16 + fr;
            const float bias = bq[n];
            #pragma unroll
            for (int mi = 0; mi < 4; ++mi)
                #pragma unroll
                for (int j = 0; j < 4; ++j) {
                    const int m = wr*64 + mi*16 + fg*4 + j;
                    Qws[(size_t)m * A_ + n] = acc[mi][ni][j] + bias;
                }
        }
    } else {
        const float* bvrow = bv + (size_t)s * A_;
        #pragma unroll
        for (int ni = 0; ni < 4; ++ni) {
            const int n = tn*128 + wc*64 + ni*16 + fr;
            const float bias = bvrow[n];
            #pragma unroll
            for (int mi = 0; mi < 4; ++mi)
                #pragma unroll
                for (int j = 0; j < 4; ++j) {
                    const int b = wr*64 + mi*16 + fg*4 + j;
                    Vws[(((size_t)s * B_ + b) * 3 + tm) * A_ + n] = (bf16_t)(acc[mi][ni][j] + bias);
                }
        }
    }
}

// ============================================================================
extern "C" void kernel_launch(void* const* d_in, const int* in_sizes, int n_in,
                              void* d_out, int out_size, void* d_ws, size_t ws_size,
                              hipStream_t stream)
{
    const float* topic = (const float*)d_in[0];
    const float* image = (const float*)d_in[1];
    const float* text  = (const float*)d_in[2];
    const float* Wq    = (const float*)d_in[3];
    const float* bq    = (const float*)d_in[4];
    const float* Wv    = (const float*)d_in[5];
    const float* bv    = (const float*)d_in[6];
    float* out = (float*)d_out;

    const size_t szAct = (size_t)(TOPIC_N + 2 * IMG_N) * sizeof(bf16_t);  // 25,362,432
    const size_t szV   = (size_t)S_ * B_ * 3 * A_ * sizeof(bf16_t);       // 37,748,736
    const size_t szQ   = (size_t)B_ * A_ * sizeof(float);                 //    393,216
    const size_t need  = szAct + szV + szQ;                               // ~63.5 MB

    if (ws_size >= need) {
        char* w = (char*)d_ws;
        bf16_t* actB = (bf16_t*)w;  w += szAct;
        bf16_t* Vws  = (bf16_t*)w;  w += szV;
        float*  Qws  = (float*) w;

        convert_kernel<<<(TOPIC_N + 2 * IMG_N) / 8 / 256, 256, 0, stream>>>(topic, image, text, actB);
        gemm_fused<<<772, 512, 0, stream>>>(Wv, Wq, actB, bq, bv, Vws, Qws);
        mm_attn_kernel<<<S_ * B_ / 4, 256, 0, stream>>>(Vws, Qws, out);
    } else {
        bf16_t* Vws = (bf16_t*)d_ws;
        float*  Qws = (float*)((char*)d_ws + szV);
        mm_gemm_kernel<<<S_ * 18 + 6, 256, 0, stream>>>(topic, image, text, Wq, bq, Wv, bv, Vws, Qws);
        mm_attn_kernel<<<S_ * B_ / 4, 256, 0, stream>>>(Vws, Qws, out);
    }
}